// Round 3
// baseline (1725.820 us; speedup 1.0000x reference)
//
#include <hip/hip_runtime.h>
#include <math.h>

#define BTOT 131072
#define NBK 3
#define SS 16
#define NA 9
#define BAD 25      // SS+NA
#define VD 128
#define CM 10
#define FLAT 75     // NBK*BAD
#define OUTD 51     // NBK*SS + 3
#define EPS 1e-8f

// ---- folded-weight image layout (float offsets); identical in ws and LDS ----
// rows padded to multiples of 4 floats for ds_read_b128
#define O_GQK  0        // 25 x 28  (full Wq^T Wk)
#define O_GQQ  700      // 25 x 28  (lower-tri, off-diag x2, of Wq^T Wq)
#define O_GKK  1400     // 25 x 28  (lower-tri, off-diag x2, of Wk^T Wk)
#define O_V1   2100     // 28: Wq^T bk
#define O_V2   2128     // 28: Wk^T bq
#define O_VQ   2156     // 28: Wq^T bq
#define O_VK   2184     // 28: Wk^T bk
#define O_C    2212     // c0=bq.bk, cq=bq.bq, ck=bk.bk, pad
#define O_M    2216     // 128 x 28: 2*(W1 @ Wv)   (x2 folded for tanh)
#define O_MB   5800     // 128:      2*(W1 @ bv + b1)
#define O_W2T  5928     // 128 x 16: W2 transposed [d][o]
#define O_B2   7976     // 16
#define O_WC1  7992     // 10 x 76
#define O_BC1  8752     // 12
#define O_WC2  8764     // 3 x 12
#define O_BC2  8800     // 4
#define LDS_F  8804     // total floats (= 2201 float4)

__device__ __forceinline__ float fast_sigmoid(float x) {
    return __builtin_amdgcn_rcpf(1.0f + __expf(-x));
}

// one output element of the folded-weight image per thread
__global__ void prep_kernel(const float* __restrict__ Wq, const float* __restrict__ bq,
                            const float* __restrict__ Wk, const float* __restrict__ bk,
                            const float* __restrict__ Wv, const float* __restrict__ bv,
                            const float* __restrict__ W1, const float* __restrict__ b1,
                            const float* __restrict__ W2, const float* __restrict__ b2,
                            const float* __restrict__ Wc1, const float* __restrict__ bc1,
                            const float* __restrict__ Wc2, const float* __restrict__ bc2,
                            float* __restrict__ ws) {
    int idx = blockIdx.x * 256 + threadIdx.x;
    if (idx >= LDS_F) return;
    float val = 0.0f;
    if (idx < O_GQQ) {                       // Gqk full
        int e = idx / 28, f = idx % 28;
        if (f < BAD) {
            float s = 0.f;
            for (int d = 0; d < VD; ++d) s += Wq[d * BAD + e] * Wk[d * BAD + f];
            val = s;
        }
    } else if (idx < O_GKK) {                // Gqq lower-tri scaled
        int j = idx - O_GQQ; int e = j / 28, f = j % 28;
        if (f < BAD && f <= e) {
            float s = 0.f;
            for (int d = 0; d < VD; ++d) s += Wq[d * BAD + e] * Wq[d * BAD + f];
            val = (f == e) ? s : 2.0f * s;
        }
    } else if (idx < O_V1) {                 // Gkk lower-tri scaled
        int j = idx - O_GKK; int e = j / 28, f = j % 28;
        if (f < BAD && f <= e) {
            float s = 0.f;
            for (int d = 0; d < VD; ++d) s += Wk[d * BAD + e] * Wk[d * BAD + f];
            val = (f == e) ? s : 2.0f * s;
        }
    } else if (idx < O_V2) {
        int e = idx - O_V1;
        if (e < BAD) { float s = 0.f; for (int d = 0; d < VD; ++d) s += Wq[d * BAD + e] * bk[d]; val = s; }
    } else if (idx < O_VQ) {
        int e = idx - O_V2;
        if (e < BAD) { float s = 0.f; for (int d = 0; d < VD; ++d) s += Wk[d * BAD + e] * bq[d]; val = s; }
    } else if (idx < O_VK) {
        int e = idx - O_VQ;
        if (e < BAD) { float s = 0.f; for (int d = 0; d < VD; ++d) s += Wq[d * BAD + e] * bq[d]; val = s; }
    } else if (idx < O_C) {
        int e = idx - O_VK;
        if (e < BAD) { float s = 0.f; for (int d = 0; d < VD; ++d) s += Wk[d * BAD + e] * bk[d]; val = s; }
    } else if (idx < O_M) {
        int j = idx - O_C;
        if (j == 0) { float s = 0.f; for (int d = 0; d < VD; ++d) s += bq[d] * bk[d]; val = s; }
        else if (j == 1) { float s = 0.f; for (int d = 0; d < VD; ++d) s += bq[d] * bq[d]; val = s; }
        else if (j == 2) { float s = 0.f; for (int d = 0; d < VD; ++d) s += bk[d] * bk[d]; val = s; }
    } else if (idx < O_MB) {                 // 2 * W1 @ Wv
        int j = idx - O_M; int r = j / 28, c = j % 28;
        if (c < BAD) {
            float s = 0.f;
            for (int k = 0; k < VD; ++k) s += W1[r * VD + k] * Wv[k * BAD + c];
            val = 2.0f * s;
        }
    } else if (idx < O_W2T) {                // 2 * (W1 @ bv + b1)
        int d = idx - O_MB;
        float s = b1[d];
        for (int k = 0; k < VD; ++k) s += W1[d * VD + k] * bv[k];
        val = 2.0f * s;
    } else if (idx < O_B2) {
        int j = idx - O_W2T; int d = j / 16, o = j % 16;
        val = W2[o * VD + d];
    } else if (idx < O_WC1) {
        val = b2[idx - O_B2];
    } else if (idx < O_BC1) {
        int j = idx - O_WC1; int m = j / 76, e = j % 76;
        if (e < FLAT) val = Wc1[m * FLAT + e];
    } else if (idx < O_WC2) {
        int m = idx - O_BC1;
        if (m < CM) val = bc1[m];
    } else if (idx < O_BC2) {
        int j = idx - O_WC2; int o = j / 12, m = j % 12;
        if (m < CM) val = Wc2[o * CM + m];
    } else {
        int o = idx - O_BC2;
        if (o < 3) val = bc2[o];
    }
    ws[idx] = val;
}

// 2 threads per element (h = d-loop half); 256 threads -> 128 elements/block
__global__ __launch_bounds__(256, 3) void main_kernel(
    const float* __restrict__ states, const float* __restrict__ action,
    const int* __restrict__ block_id,
    const float* __restrict__ ws, float* __restrict__ out) {
    __shared__ __align__(16) float lds[LDS_F];
    {
        const float4* s4 = (const float4*)ws;
        float4* d4 = (float4*)lds;
        for (int i = threadIdx.x; i < LDS_F / 4; i += 256) d4[i] = s4[i];
    }
    __syncthreads();

    int t = threadIdx.x;
    int elem = blockIdx.x * 128 + (t >> 1);
    int h = t & 1;

    const float* st = states + (long)elem * (NBK * SS);
    const float* ac = action + (long)elem * NA;
    const int* bid = block_id + (long)elem * NBK;

    // ---- build ba[3][25] ----
    float ba[NBK * BAD];
    #pragma unroll
    for (int i = 0; i < NBK; ++i) {
        const float4* s4 = (const float4*)(st + i * SS);
        #pragma unroll
        for (int w = 0; w < 4; ++w) {
            float4 v = s4[w];
            ba[i * BAD + w * 4 + 0] = v.x;
            ba[i * BAD + w * 4 + 1] = v.y;
            ba[i * BAD + w * 4 + 2] = v.z;
            ba[i * BAD + w * 4 + 3] = v.w;
        }
        bool sel = (bid[i] == 1);
        #pragma unroll
        for (int c = 0; c < NA; ++c)
            ba[i * BAD + SS + c] = sel ? ac[c] : -1.0f;
    }

    // ---- confidence MLP ----
    float conf0, conf1, conf2;
    {
        float hm[CM];
        #pragma unroll
        for (int m = 0; m < CM; ++m) {
            float s = lds[O_BC1 + m];
            #pragma unroll
            for (int e = 0; e < FLAT; ++e) s += lds[O_WC1 + m * 76 + e] * ba[e];
            hm[m] = fast_sigmoid(s);
        }
        float c[3];
        #pragma unroll
        for (int o = 0; o < 3; ++o) {
            float s = lds[O_BC2 + o];
            #pragma unroll
            for (int m = 0; m < CM; ++m) s += lds[O_WC2 + o * 12 + m] * hm[m];
            c[o] = fast_sigmoid(s);
        }
        conf0 = c[0]; conf1 = c[1]; conf2 = c[2];
    }

    // ---- scores ----
    float s1[NBK], s2[NBK];
    #pragma unroll
    for (int p = 0; p < NBK; ++p) {
        float a1 = 0.f, a2 = 0.f;
        #pragma unroll
        for (int e = 0; e < BAD; ++e) {
            a1 += lds[O_V1 + e] * ba[p * BAD + e];
            a2 += lds[O_V2 + e] * ba[p * BAD + e];
        }
        s1[p] = a1; s2[p] = a2;
    }
    float c0 = lds[O_C + 0], cq = lds[O_C + 1], ck = lds[O_C + 2];

    float num[NBK][NBK];
    #pragma unroll
    for (int j = 0; j < NBK; ++j) {
        float tv[BAD];
        #pragma unroll
        for (int e = 0; e < BAD; ++e) {
            float s = 0.f;
            #pragma unroll
            for (int f = 0; f < BAD; ++f) s += lds[O_GQK + e * 28 + f] * ba[j * BAD + f];
            tv[e] = s;
        }
        #pragma unroll
        for (int i = 0; i < NBK; ++i) {
            float s = 0.f;
            #pragma unroll
            for (int e = 0; e < BAD; ++e) s += ba[i * BAD + e] * tv[e];
            num[i][j] = s + s1[i] + s2[j] + c0;
        }
    }

    float qn2[NBK], kn2[NBK];
    #pragma unroll
    for (int p = 0; p < NBK; ++p) {
        float sq = 0.f, sk = 0.f;
        #pragma unroll
        for (int e = 0; e < BAD; ++e) {
            float pq = 0.f, pk = 0.f;
            #pragma unroll
            for (int f = 0; f <= e; ++f) {
                pq += lds[O_GQQ + e * 28 + f] * ba[p * BAD + f];
                pk += lds[O_GKK + e * 28 + f] * ba[p * BAD + f];
            }
            sq += ba[p * BAD + e] * pq;
            sk += ba[p * BAD + e] * pk;
        }
        float dq = 0.f, dk = 0.f;
        #pragma unroll
        for (int e = 0; e < BAD; ++e) {
            dq += lds[O_VQ + e] * ba[p * BAD + e];
            dk += lds[O_VK + e] * ba[p * BAD + e];
        }
        qn2[p] = sq + 2.0f * dq + cq;
        kn2[p] = sk + 2.0f * dk + ck;
    }

    // ---- softmax ----
    float att[NBK][NBK];
    #pragma unroll
    for (int i = 0; i < NBK; ++i) {
        float qn = __builtin_amdgcn_sqrtf(fmaxf(qn2[i], 0.0f));
        float dv[NBK];
        #pragma unroll
        for (int j = 0; j < NBK; ++j) {
            float kn = __builtin_amdgcn_sqrtf(fmaxf(kn2[j], 0.0f));
            dv[j] = num[i][j] * __builtin_amdgcn_rcpf(fmaxf(qn * kn, EPS));
        }
        float mx = fmaxf(dv[0], fmaxf(dv[1], dv[2]));
        float e0 = __expf(dv[0] - mx);
        float e1 = __expf(dv[1] - mx);
        float e2 = __expf(dv[2] - mx);
        float inv = __builtin_amdgcn_rcpf(e0 + e1 + e2);
        att[i][0] = e0 * inv;
        att[i][1] = e1 * inv;
        att[i][2] = e2 * inv;
    }

    // ---- r2 init: base (states) + b2 ONLY in half h==0 (pair is summed later) ----
    float r2[48];
    #pragma unroll
    for (int i = 0; i < NBK; ++i)
        #pragma unroll
        for (int o = 0; o < SS; ++o)
            r2[i * SS + o] = (h == 0) ? (ba[i * BAD + o] + lds[O_B2 + o]) : 0.0f;

    // ---- a_tilde (in place) ----
    #pragma unroll
    for (int e = 0; e < BAD; ++e) {
        float b0 = ba[0 * BAD + e], b1v = ba[1 * BAD + e], b2v = ba[2 * BAD + e];
        #pragma unroll
        for (int i = 0; i < NBK; ++i)
            ba[i * BAD + e] = att[i][0] * b0 + att[i][1] * b1v + att[i][2] * b2v;
    }

    // ---- half of the main VD loop per thread ----
    int d0 = h * 64;
    for (int dd = 0; dd < 64; ++dd) {
        int d = d0 + dd;
        const float* Mr = lds + O_M + d * 28;
        float m0 = lds[O_MB + d];
        float acc0 = m0, acc1 = m0, acc2 = m0;
        #pragma unroll
        for (int e = 0; e < BAD; ++e) {
            float m = Mr[e];
            acc0 += m * ba[0 * BAD + e];
            acc1 += m * ba[1 * BAD + e];
            acc2 += m * ba[2 * BAD + e];
        }
        // tanh(x) = 1 - 2/(1+exp(2x)); acc already = 2x (M,mb doubled in prep)
        float r10 = fmaf(-2.0f, __builtin_amdgcn_rcpf(1.0f + __expf(acc0)), 1.0f);
        float r11 = fmaf(-2.0f, __builtin_amdgcn_rcpf(1.0f + __expf(acc1)), 1.0f);
        float r12 = fmaf(-2.0f, __builtin_amdgcn_rcpf(1.0f + __expf(acc2)), 1.0f);
        const float* w2r = lds + O_W2T + d * 16;
        #pragma unroll
        for (int o = 0; o < SS; ++o) {
            float w = w2r[o];
            r2[0 * SS + o] += r10 * w;
            r2[1 * SS + o] += r11 * w;
            r2[2 * SS + o] += r12 * w;
        }
    }

    // ---- combine halves (lane pair t, t^1) ----
    #pragma unroll
    for (int k = 0; k < 48; ++k) {
        float o = __shfl_xor(r2[k], 1, 64);
        r2[k] += o;
    }

    float* op = out + (long)elem * OUTD;
    if (h == 0) {
        #pragma unroll
        for (int k = 0; k < 24; ++k) op[k] = r2[k];
    } else {
        #pragma unroll
        for (int k = 24; k < 48; ++k) op[k] = r2[k];
        op[48] = conf0; op[49] = conf1; op[50] = conf2;
    }
}

extern "C" void kernel_launch(void* const* d_in, const int* in_sizes, int n_in,
                              void* d_out, int out_size, void* d_ws, size_t ws_size,
                              hipStream_t stream) {
    const float* states = (const float*)d_in[0];
    const float* action = (const float*)d_in[1];
    const int* block_id = (const int*)d_in[2];
    const float* Wq = (const float*)d_in[3];
    const float* bq = (const float*)d_in[4];
    const float* Wk = (const float*)d_in[5];
    const float* bk = (const float*)d_in[6];
    const float* Wv = (const float*)d_in[7];
    const float* bv = (const float*)d_in[8];
    const float* W1 = (const float*)d_in[9];
    const float* b1 = (const float*)d_in[10];
    const float* W2 = (const float*)d_in[11];
    const float* b2 = (const float*)d_in[12];
    const float* Wc1 = (const float*)d_in[13];
    const float* bc1 = (const float*)d_in[14];
    const float* Wc2 = (const float*)d_in[15];
    const float* bc2 = (const float*)d_in[16];
    float* out = (float*)d_out;
    float* ws = (float*)d_ws;

    hipLaunchKernelGGL(prep_kernel, dim3((LDS_F + 255) / 256), dim3(256), 0, stream,
                       Wq, bq, Wk, bk, Wv, bv, W1, b1, W2, b2, Wc1, bc1, Wc2, bc2, ws);
    hipLaunchKernelGGL(main_kernel, dim3(BTOT / 128), dim3(256), 0, stream,
                       states, action, block_id, ws, out);
}

// Round 4
// 764.015 us; speedup vs baseline: 2.2589x; 2.2589x over previous
//
#include <hip/hip_runtime.h>
#include <math.h>

#define BTOT 131072
#define NBK 3
#define SS 16
#define NA 9
#define BAD 25      // SS+NA
#define STR 28      // padded row stride (float4-aligned)
#define VD 128
#define CM 10
#define OUTD 51     // NBK*SS + 3
#define EPS 1e-8f

// ---- folded-weight image layout (float offsets); identical in ws and LDS ----
// every row padded to 4-float multiples, pads are ZERO (safe to FMA)
#define O_GQK  0        // 25 x 28  full Wq^T Wk
#define O_GQQ  700      // 25 x 28  lower-tri (off-diag x2) of Wq^T Wq
#define O_GKK  1400     // 25 x 28  lower-tri (off-diag x2) of Wk^T Wk
#define O_V1   2100     // 28: Wq^T bk
#define O_V2   2128     // 28: Wk^T bq
#define O_VQ   2156     // 28: Wq^T bq
#define O_VK   2184     // 28: Wk^T bk
#define O_C    2212     // c0=bq.bk, cq=bq.bq, ck=bk.bk, pad
#define O_M    2216     // 128 x 28: 2*(W1 @ Wv)   (x2 folded for tanh)
#define O_MB   5800     // 128:      2*(W1 @ bv + b1)
#define O_W2T  5928     // 128 x 16: W2 transposed [d][o]
#define O_B2   7976     // 16
#define O_WC1  7992     // 10 x 84: Wc1 repacked [m][i*28+f], f<25
#define O_BC1  8832     // 12
#define O_WC2  8844     // 3 x 12
#define O_BC2  8880     // 4
#define LDS_F  8884     // total floats (= 2221 float4)

__device__ __forceinline__ float fast_sigmoid(float x) {
    return __builtin_amdgcn_rcpf(1.0f + __expf(-x));
}

__device__ __forceinline__ void load28(float* r, const float* p) {
    const float4* p4 = (const float4*)p;
    #pragma unroll
    for (int k = 0; k < 7; ++k) {
        float4 v = p4[k];
        r[4 * k + 0] = v.x; r[4 * k + 1] = v.y; r[4 * k + 2] = v.z; r[4 * k + 3] = v.w;
    }
}

// one output element of the folded-weight image per thread
__global__ void prep_kernel(const float* __restrict__ Wq, const float* __restrict__ bq,
                            const float* __restrict__ Wk, const float* __restrict__ bk,
                            const float* __restrict__ Wv, const float* __restrict__ bv,
                            const float* __restrict__ W1, const float* __restrict__ b1,
                            const float* __restrict__ W2, const float* __restrict__ b2,
                            const float* __restrict__ Wc1, const float* __restrict__ bc1,
                            const float* __restrict__ Wc2, const float* __restrict__ bc2,
                            float* __restrict__ ws) {
    int idx = blockIdx.x * 256 + threadIdx.x;
    if (idx >= LDS_F) return;
    float val = 0.0f;
    if (idx < O_GQQ) {                       // Gqk full
        int e = idx / STR, f = idx % STR;
        if (f < BAD) {
            float s = 0.f;
            for (int d = 0; d < VD; ++d) s += Wq[d * BAD + e] * Wk[d * BAD + f];
            val = s;
        }
    } else if (idx < O_GKK) {                // Gqq lower-tri scaled
        int j = idx - O_GQQ; int e = j / STR, f = j % STR;
        if (f < BAD && f <= e) {
            float s = 0.f;
            for (int d = 0; d < VD; ++d) s += Wq[d * BAD + e] * Wq[d * BAD + f];
            val = (f == e) ? s : 2.0f * s;
        }
    } else if (idx < O_V1) {                 // Gkk lower-tri scaled
        int j = idx - O_GKK; int e = j / STR, f = j % STR;
        if (f < BAD && f <= e) {
            float s = 0.f;
            for (int d = 0; d < VD; ++d) s += Wk[d * BAD + e] * Wk[d * BAD + f];
            val = (f == e) ? s : 2.0f * s;
        }
    } else if (idx < O_V2) {
        int e = idx - O_V1;
        if (e < BAD) { float s = 0.f; for (int d = 0; d < VD; ++d) s += Wq[d * BAD + e] * bk[d]; val = s; }
    } else if (idx < O_VQ) {
        int e = idx - O_V2;
        if (e < BAD) { float s = 0.f; for (int d = 0; d < VD; ++d) s += Wk[d * BAD + e] * bq[d]; val = s; }
    } else if (idx < O_VK) {
        int e = idx - O_VQ;
        if (e < BAD) { float s = 0.f; for (int d = 0; d < VD; ++d) s += Wq[d * BAD + e] * bq[d]; val = s; }
    } else if (idx < O_C) {
        int e = idx - O_VK;
        if (e < BAD) { float s = 0.f; for (int d = 0; d < VD; ++d) s += Wk[d * BAD + e] * bk[d]; val = s; }
    } else if (idx < O_M) {
        int j = idx - O_C;
        if (j == 0) { float s = 0.f; for (int d = 0; d < VD; ++d) s += bq[d] * bk[d]; val = s; }
        else if (j == 1) { float s = 0.f; for (int d = 0; d < VD; ++d) s += bq[d] * bq[d]; val = s; }
        else if (j == 2) { float s = 0.f; for (int d = 0; d < VD; ++d) s += bk[d] * bk[d]; val = s; }
    } else if (idx < O_MB) {                 // 2 * W1 @ Wv
        int j = idx - O_M; int r = j / STR, c = j % STR;
        if (c < BAD) {
            float s = 0.f;
            for (int k = 0; k < VD; ++k) s += W1[r * VD + k] * Wv[k * BAD + c];
            val = 2.0f * s;
        }
    } else if (idx < O_W2T) {                // 2 * (W1 @ bv + b1)
        int d = idx - O_MB;
        float s = b1[d];
        for (int k = 0; k < VD; ++k) s += W1[d * VD + k] * bv[k];
        val = 2.0f * s;
    } else if (idx < O_B2) {
        int j = idx - O_W2T; int d = j / 16, o = j % 16;
        val = W2[o * VD + d];
    } else if (idx < O_WC1) {
        val = b2[idx - O_B2];
    } else if (idx < O_BC1) {                // Wc1 repacked [m][i*28+f]
        int j = idx - O_WC1; int m = j / 84; int r = j % 84; int i = r / STR; int f = r % STR;
        if (f < BAD) val = Wc1[m * (NBK * BAD) + i * BAD + f];
    } else if (idx < O_WC2) {
        int m = idx - O_BC1;
        if (m < CM) val = bc1[m];
    } else if (idx < O_BC2) {
        int j = idx - O_WC2; int o = j / 12, m = j % 12;
        if (m < CM) val = Wc2[o * CM + m];
    } else {
        int o = idx - O_BC2;
        if (o < 3) val = bc2[o];
    }
    ws[idx] = val;
}

// one thread per element; all weight reads are broadcast ds_read_b128 from LDS
__global__ __launch_bounds__(256) void main_kernel(
    const float* __restrict__ states, const float* __restrict__ action,
    const int* __restrict__ block_id,
    const float* __restrict__ ws, float* __restrict__ out) {
    __shared__ __align__(16) float lds[LDS_F];
    {
        const float4* s4 = (const float4*)ws;
        float4* d4 = (float4*)lds;
        for (int i = threadIdx.x; i < LDS_F / 4; i += 256) d4[i] = s4[i];
    }
    __syncthreads();

    int elem = blockIdx.x * 256 + threadIdx.x;

    const float* st = states + (long)elem * (NBK * SS);
    const float* ac = action + (long)elem * NA;
    const int* bid = block_id + (long)elem * NBK;

    // ---- build ba[3][28], pads zero ----
    float ba[NBK * STR];
    #pragma unroll
    for (int i = 0; i < NBK; ++i) {
        const float4* s4 = (const float4*)(st + i * SS);  // 16B aligned: elem*192 + i*64
        #pragma unroll
        for (int w = 0; w < 4; ++w) {
            float4 v = s4[w];
            ba[i * STR + w * 4 + 0] = v.x;
            ba[i * STR + w * 4 + 1] = v.y;
            ba[i * STR + w * 4 + 2] = v.z;
            ba[i * STR + w * 4 + 3] = v.w;
        }
        bool sel = (bid[i] == 1);
        #pragma unroll
        for (int c = 0; c < NA; ++c)
            ba[i * STR + SS + c] = sel ? ac[c] : -1.0f;
        ba[i * STR + 25] = 0.0f;
        ba[i * STR + 26] = 0.0f;
        ba[i * STR + 27] = 0.0f;
    }

    // ---- confidence MLP ----
    float conf0, conf1, conf2;
    {
        float hm[CM];
        #pragma unroll
        for (int m = 0; m < CM; ++m) {
            float s = lds[O_BC1 + m];
            #pragma unroll
            for (int i = 0; i < NBK; ++i) {
                float row[STR];
                load28(row, lds + O_WC1 + m * 84 + i * STR);
                #pragma unroll
                for (int f = 0; f < STR; ++f) s += row[f] * ba[i * STR + f];
            }
            hm[m] = fast_sigmoid(s);
        }
        float c[3];
        #pragma unroll
        for (int o = 0; o < 3; ++o) {
            float s = lds[O_BC2 + o];
            #pragma unroll
            for (int m = 0; m < CM; ++m) s += lds[O_WC2 + o * 12 + m] * hm[m];
            c[o] = fast_sigmoid(s);
        }
        conf0 = c[0]; conf1 = c[1]; conf2 = c[2];
    }

    // ---- linear score terms ----
    float s1[NBK], s2[NBK], dq[NBK], dk[NBK];
    {
        float rv1[STR], rv2[STR], rvq[STR], rvk[STR];
        load28(rv1, lds + O_V1);
        load28(rv2, lds + O_V2);
        load28(rvq, lds + O_VQ);
        load28(rvk, lds + O_VK);
        #pragma unroll
        for (int p = 0; p < NBK; ++p) {
            float a1 = 0.f, a2 = 0.f, aq = 0.f, ak = 0.f;
            #pragma unroll
            for (int e = 0; e < STR; ++e) {
                float b = ba[p * STR + e];
                a1 += rv1[e] * b;
                a2 += rv2[e] * b;
                aq += rvq[e] * b;
                ak += rvk[e] * b;
            }
            s1[p] = a1; s2[p] = a2; dq[p] = aq; dk[p] = ak;
        }
    }
    float c0 = lds[O_C + 0], cq = lds[O_C + 1], ck = lds[O_C + 2];

    // ---- bilinear numerators: row-at-a-time over Gqk ----
    float num[NBK][NBK];
    #pragma unroll
    for (int i = 0; i < NBK; ++i)
        #pragma unroll
        for (int j = 0; j < NBK; ++j) num[i][j] = 0.0f;
    #pragma unroll
    for (int e = 0; e < BAD; ++e) {
        float row[STR];
        load28(row, lds + O_GQK + e * STR);
        float t[NBK];
        #pragma unroll
        for (int j = 0; j < NBK; ++j) {
            float s = 0.f;
            #pragma unroll
            for (int f = 0; f < STR; ++f) s += row[f] * ba[j * STR + f];
            t[j] = s;
        }
        #pragma unroll
        for (int i = 0; i < NBK; ++i)
            #pragma unroll
            for (int j = 0; j < NBK; ++j)
                num[i][j] += ba[i * STR + e] * t[j];
    }

    // ---- quadratic forms via scaled lower triangles ----
    float qn2[NBK] = {0.f, 0.f, 0.f}, kn2[NBK] = {0.f, 0.f, 0.f};
    #pragma unroll
    for (int e = 0; e < BAD; ++e) {
        const int nch = (e + 4) >> 2;  // ceil((e+1)/4); pads beyond e are zero
        const float4* rq4 = (const float4*)(lds + O_GQQ + e * STR);
        const float4* rk4 = (const float4*)(lds + O_GKK + e * STR);
        float pq[NBK] = {0.f, 0.f, 0.f}, pk[NBK] = {0.f, 0.f, 0.f};
        #pragma unroll
        for (int cch = 0; cch < nch; ++cch) {
            float4 q4 = rq4[cch];
            float4 k4 = rk4[cch];
            #pragma unroll
            for (int p = 0; p < NBK; ++p) {
                const float* bp = ba + p * STR + 4 * cch;
                pq[p] += q4.x * bp[0] + q4.y * bp[1] + q4.z * bp[2] + q4.w * bp[3];
                pk[p] += k4.x * bp[0] + k4.y * bp[1] + k4.z * bp[2] + k4.w * bp[3];
            }
        }
        #pragma unroll
        for (int p = 0; p < NBK; ++p) {
            qn2[p] += ba[p * STR + e] * pq[p];
            kn2[p] += ba[p * STR + e] * pk[p];
        }
    }
    #pragma unroll
    for (int p = 0; p < NBK; ++p) {
        qn2[p] += 2.0f * dq[p] + cq;
        kn2[p] += 2.0f * dk[p] + ck;
    }

    // ---- softmax over j ----
    float att[NBK][NBK];
    {
        float kn[NBK];
        #pragma unroll
        for (int j = 0; j < NBK; ++j) kn[j] = __builtin_amdgcn_sqrtf(fmaxf(kn2[j], 0.0f));
        #pragma unroll
        for (int i = 0; i < NBK; ++i) {
            float qn = __builtin_amdgcn_sqrtf(fmaxf(qn2[i], 0.0f));
            float dv[NBK];
            #pragma unroll
            for (int j = 0; j < NBK; ++j)
                dv[j] = (num[i][j] + s1[i] + s2[j] + c0) *
                        __builtin_amdgcn_rcpf(fmaxf(qn * kn[j], EPS));
            float mx = fmaxf(dv[0], fmaxf(dv[1], dv[2]));
            float e0 = __expf(dv[0] - mx);
            float e1 = __expf(dv[1] - mx);
            float e2 = __expf(dv[2] - mx);
            float inv = __builtin_amdgcn_rcpf(e0 + e1 + e2);
            att[i][0] = e0 * inv;
            att[i][1] = e1 * inv;
            att[i][2] = e2 * inv;
        }
    }

    // ---- r2 init from base (states) + b2, before ba overwrite ----
    float r2[NBK * SS];
    {
        float b2r[16];
        load28:;  // (label unused; keep simple)
        const float4* b4 = (const float4*)(lds + O_B2);
        #pragma unroll
        for (int w = 0; w < 4; ++w) {
            float4 v = b4[w];
            b2r[4 * w + 0] = v.x; b2r[4 * w + 1] = v.y; b2r[4 * w + 2] = v.z; b2r[4 * w + 3] = v.w;
        }
        #pragma unroll
        for (int i = 0; i < NBK; ++i)
            #pragma unroll
            for (int o = 0; o < SS; ++o) r2[i * SS + o] = ba[i * STR + o] + b2r[o];
    }

    // ---- a_tilde_i = sum_j att[i][j] * ba_j (in place; pads stay zero) ----
    #pragma unroll
    for (int e = 0; e < BAD; ++e) {
        float b0 = ba[0 * STR + e], b1v = ba[1 * STR + e], b2v = ba[2 * STR + e];
        ba[0 * STR + e] = att[0][0] * b0 + att[0][1] * b1v + att[0][2] * b2v;
        ba[1 * STR + e] = att[1][0] * b0 + att[1][1] * b1v + att[1][2] * b2v;
        ba[2 * STR + e] = att[2][0] * b0 + att[2][1] * b1v + att[2][2] * b2v;
    }

    // ---- main VD loop ----
    #pragma unroll 2
    for (int d = 0; d < VD; ++d) {
        float row[STR];
        load28(row, lds + O_M + d * STR);
        float m0 = lds[O_MB + d];
        float acc0 = m0, acc1 = m0, acc2 = m0;
        #pragma unroll
        for (int e = 0; e < STR; ++e) {
            float m = row[e];
            acc0 += m * ba[0 * STR + e];
            acc1 += m * ba[1 * STR + e];
            acc2 += m * ba[2 * STR + e];
        }
        // tanh(x) = 1 - 2/(1+exp(2x)); acc already = 2x (M,mb doubled in prep)
        float r10 = fmaf(-2.0f, __builtin_amdgcn_rcpf(1.0f + __expf(acc0)), 1.0f);
        float r11 = fmaf(-2.0f, __builtin_amdgcn_rcpf(1.0f + __expf(acc1)), 1.0f);
        float r12 = fmaf(-2.0f, __builtin_amdgcn_rcpf(1.0f + __expf(acc2)), 1.0f);
        const float4* w4 = (const float4*)(lds + O_W2T + d * 16);
        #pragma unroll
        for (int cch = 0; cch < 4; ++cch) {
            float4 w = w4[cch];
            r2[0 * SS + 4 * cch + 0] += r10 * w.x;
            r2[0 * SS + 4 * cch + 1] += r10 * w.y;
            r2[0 * SS + 4 * cch + 2] += r10 * w.z;
            r2[0 * SS + 4 * cch + 3] += r10 * w.w;
            r2[1 * SS + 4 * cch + 0] += r11 * w.x;
            r2[1 * SS + 4 * cch + 1] += r11 * w.y;
            r2[1 * SS + 4 * cch + 2] += r11 * w.z;
            r2[1 * SS + 4 * cch + 3] += r11 * w.w;
            r2[2 * SS + 4 * cch + 0] += r12 * w.x;
            r2[2 * SS + 4 * cch + 1] += r12 * w.y;
            r2[2 * SS + 4 * cch + 2] += r12 * w.z;
            r2[2 * SS + 4 * cch + 3] += r12 * w.w;
        }
    }

    // ---- store ----
    float* op = out + (long)elem * OUTD;
    #pragma unroll
    for (int k = 0; k < NBK * SS; ++k) op[k] = r2[k];
    op[48] = conf0;
    op[49] = conf1;
    op[50] = conf2;
}

extern "C" void kernel_launch(void* const* d_in, const int* in_sizes, int n_in,
                              void* d_out, int out_size, void* d_ws, size_t ws_size,
                              hipStream_t stream) {
    const float* states = (const float*)d_in[0];
    const float* action = (const float*)d_in[1];
    const int* block_id = (const int*)d_in[2];
    const float* Wq = (const float*)d_in[3];
    const float* bq = (const float*)d_in[4];
    const float* Wk = (const float*)d_in[5];
    const float* bk = (const float*)d_in[6];
    const float* Wv = (const float*)d_in[7];
    const float* bv = (const float*)d_in[8];
    const float* W1 = (const float*)d_in[9];
    const float* b1 = (const float*)d_in[10];
    const float* W2 = (const float*)d_in[11];
    const float* b2 = (const float*)d_in[12];
    const float* Wc1 = (const float*)d_in[13];
    const float* bc1 = (const float*)d_in[14];
    const float* Wc2 = (const float*)d_in[15];
    const float* bc2 = (const float*)d_in[16];
    float* out = (float*)d_out;
    float* ws = (float*)d_ws;

    hipLaunchKernelGGL(prep_kernel, dim3((LDS_F + 255) / 256), dim3(256), 0, stream,
                       Wq, bq, Wk, bk, Wv, bv, W1, b1, W2, b2, Wc1, bc1, Wc2, bc2, ws);
    hipLaunchKernelGGL(main_kernel, dim3(BTOT / 256), dim3(256), 0, stream,
                       states, action, block_id, ws, out);
}

// Round 5
// 470.047 us; speedup vs baseline: 3.6716x; 1.6254x over previous
//
#include <hip/hip_runtime.h>
#include <math.h>

#define BTOT 131072
#define NBK 3
#define SS 16
#define NA 9
#define BAD 25      // SS+NA
#define STR 28      // padded LDS row stride (float4-aligned)
#define VD 128
#define CM 10
#define OUTD 51     // NBK*SS + 3
#define EPS 1e-8f

// ---- folded-weight image layout (float offsets); identical in ws and LDS ----
// every row padded to 4-float multiples, pads are ZERO
#define O_GQK  0        // 25 x 28  full Wq^T Wk
#define O_GQQ  700      // 25 x 28  lower-tri (off-diag x2) of Wq^T Wq
#define O_GKK  1400     // 25 x 28  lower-tri (off-diag x2) of Wk^T Wk
#define O_V1   2100     // 28: Wq^T bk
#define O_V2   2128     // 28: Wk^T bq
#define O_VQ   2156     // 28: Wq^T bq
#define O_VK   2184     // 28: Wk^T bk
#define O_C    2212     // c0=bq.bk, cq=bq.bq, ck=bk.bk, pad
#define O_M    2216     // 128 x 28: 2*(W1 @ Wv)   (x2 folded for tanh)
#define O_MB   5800     // 128:      2*(W1 @ bv + b1)
#define O_W2T  5928     // 128 x 16: W2 transposed [d][o]
#define O_B2   7976     // 16
#define O_WC1  7992     // 10 x 84: Wc1 repacked [m][i*28+f], f<25
#define O_BC1  8832     // 12
#define O_WC2  8844     // 3 x 12
#define O_BC2  8880     // 4
#define LDS_F  8884     // total floats (= 2221 float4)

__device__ __forceinline__ float fast_sigmoid(float x) {
    return __builtin_amdgcn_rcpf(1.0f + __expf(-x));
}

// one output element of the folded-weight image per thread
__global__ void prep_kernel(const float* __restrict__ Wq, const float* __restrict__ bq,
                            const float* __restrict__ Wk, const float* __restrict__ bk,
                            const float* __restrict__ Wv, const float* __restrict__ bv,
                            const float* __restrict__ W1, const float* __restrict__ b1,
                            const float* __restrict__ W2, const float* __restrict__ b2,
                            const float* __restrict__ Wc1, const float* __restrict__ bc1,
                            const float* __restrict__ Wc2, const float* __restrict__ bc2,
                            float* __restrict__ ws) {
    int idx = blockIdx.x * 256 + threadIdx.x;
    if (idx >= LDS_F) return;
    float val = 0.0f;
    if (idx < O_GQQ) {                       // Gqk full
        int e = idx / STR, f = idx % STR;
        if (f < BAD) {
            float s = 0.f;
            for (int d = 0; d < VD; ++d) s += Wq[d * BAD + e] * Wk[d * BAD + f];
            val = s;
        }
    } else if (idx < O_GKK) {                // Gqq lower-tri scaled
        int j = idx - O_GQQ; int e = j / STR, f = j % STR;
        if (f < BAD && f <= e) {
            float s = 0.f;
            for (int d = 0; d < VD; ++d) s += Wq[d * BAD + e] * Wq[d * BAD + f];
            val = (f == e) ? s : 2.0f * s;
        }
    } else if (idx < O_V1) {                 // Gkk lower-tri scaled
        int j = idx - O_GKK; int e = j / STR, f = j % STR;
        if (f < BAD && f <= e) {
            float s = 0.f;
            for (int d = 0; d < VD; ++d) s += Wk[d * BAD + e] * Wk[d * BAD + f];
            val = (f == e) ? s : 2.0f * s;
        }
    } else if (idx < O_V2) {
        int e = idx - O_V1;
        if (e < BAD) { float s = 0.f; for (int d = 0; d < VD; ++d) s += Wq[d * BAD + e] * bk[d]; val = s; }
    } else if (idx < O_VQ) {
        int e = idx - O_V2;
        if (e < BAD) { float s = 0.f; for (int d = 0; d < VD; ++d) s += Wk[d * BAD + e] * bq[d]; val = s; }
    } else if (idx < O_VK) {
        int e = idx - O_VQ;
        if (e < BAD) { float s = 0.f; for (int d = 0; d < VD; ++d) s += Wq[d * BAD + e] * bq[d]; val = s; }
    } else if (idx < O_C) {
        int e = idx - O_VK;
        if (e < BAD) { float s = 0.f; for (int d = 0; d < VD; ++d) s += Wk[d * BAD + e] * bk[d]; val = s; }
    } else if (idx < O_M) {
        int j = idx - O_C;
        if (j == 0) { float s = 0.f; for (int d = 0; d < VD; ++d) s += bq[d] * bk[d]; val = s; }
        else if (j == 1) { float s = 0.f; for (int d = 0; d < VD; ++d) s += bq[d] * bq[d]; val = s; }
        else if (j == 2) { float s = 0.f; for (int d = 0; d < VD; ++d) s += bk[d] * bk[d]; val = s; }
    } else if (idx < O_MB) {                 // 2 * W1 @ Wv
        int j = idx - O_M; int r = j / STR, c = j % STR;
        if (c < BAD) {
            float s = 0.f;
            for (int k = 0; k < VD; ++k) s += W1[r * VD + k] * Wv[k * BAD + c];
            val = 2.0f * s;
        }
    } else if (idx < O_W2T) {                // 2 * (W1 @ bv + b1)
        int d = idx - O_MB;
        float s = b1[d];
        for (int k = 0; k < VD; ++k) s += W1[d * VD + k] * bv[k];
        val = 2.0f * s;
    } else if (idx < O_B2) {
        int j = idx - O_W2T; int d = j / 16, o = j % 16;
        val = W2[o * VD + d];
    } else if (idx < O_WC1) {
        val = b2[idx - O_B2];
    } else if (idx < O_BC1) {                // Wc1 repacked [m][i*28+f]
        int j = idx - O_WC1; int m = j / 84; int r = j % 84; int i = r / STR; int f = r % STR;
        if (f < BAD) val = Wc1[m * (NBK * BAD) + i * BAD + f];
    } else if (idx < O_WC2) {
        int m = idx - O_BC1;
        if (m < CM) val = bc1[m];
    } else if (idx < O_BC2) {
        int j = idx - O_WC2; int o = j / 12, m = j % 12;
        if (m < CM) val = Wc2[o * CM + m];
    } else {
        int o = idx - O_BC2;
        if (o < 3) val = bc2[o];
    }
    ws[idx] = val;
}

// one thread per element; weights read directly from LDS (compiler merges to
// ds_read_b64/b128 broadcasts) — NO explicit register-row staging (R4's spill cause)
__global__ __launch_bounds__(256) void main_kernel(
    const float* __restrict__ states, const float* __restrict__ action,
    const int* __restrict__ block_id,
    const float* __restrict__ ws, float* __restrict__ out) {
    __shared__ __align__(16) float lds[LDS_F];
    {
        const float4* s4 = (const float4*)ws;
        float4* d4 = (float4*)lds;
        for (int i = threadIdx.x; i < LDS_F / 4; i += 256) d4[i] = s4[i];
    }
    __syncthreads();

    int elem = blockIdx.x * 256 + threadIdx.x;

    const float* st = states + (long)elem * (NBK * SS);
    const float* ac = action + (long)elem * NA;
    const int* bid = block_id + (long)elem * NBK;

    // ---- build ba[3][25] ----
    float ba[NBK * BAD];
    #pragma unroll
    for (int i = 0; i < NBK; ++i) {
        const float4* s4 = (const float4*)(st + i * SS);  // 16B aligned: elem*192 + i*64
        #pragma unroll
        for (int w = 0; w < 4; ++w) {
            float4 v = s4[w];
            ba[i * BAD + w * 4 + 0] = v.x;
            ba[i * BAD + w * 4 + 1] = v.y;
            ba[i * BAD + w * 4 + 2] = v.z;
            ba[i * BAD + w * 4 + 3] = v.w;
        }
        bool sel = (bid[i] == 1);
        #pragma unroll
        for (int c = 0; c < NA; ++c)
            ba[i * BAD + SS + c] = sel ? ac[c] : -1.0f;
    }

    // ---- confidence MLP ----
    float conf0, conf1, conf2;
    {
        float hm[CM];
        #pragma unroll
        for (int m = 0; m < CM; ++m) {
            float s = lds[O_BC1 + m];
            #pragma unroll
            for (int i = 0; i < NBK; ++i)
                #pragma unroll
                for (int f = 0; f < BAD; ++f)
                    s += lds[O_WC1 + m * 84 + i * STR + f] * ba[i * BAD + f];
            hm[m] = fast_sigmoid(s);
        }
        float c[3];
        #pragma unroll
        for (int o = 0; o < 3; ++o) {
            float s = lds[O_BC2 + o];
            #pragma unroll
            for (int m = 0; m < CM; ++m) s += lds[O_WC2 + o * 12 + m] * hm[m];
            c[o] = fast_sigmoid(s);
        }
        conf0 = c[0]; conf1 = c[1]; conf2 = c[2];
    }

    // ---- linear score terms ----
    float s1[NBK], s2[NBK], dq[NBK], dk[NBK];
    #pragma unroll
    for (int p = 0; p < NBK; ++p) {
        float a1 = 0.f, a2 = 0.f, aq = 0.f, ak = 0.f;
        #pragma unroll
        for (int e = 0; e < BAD; ++e) {
            float b = ba[p * BAD + e];
            a1 += lds[O_V1 + e] * b;
            a2 += lds[O_V2 + e] * b;
            aq += lds[O_VQ + e] * b;
            ak += lds[O_VK + e] * b;
        }
        s1[p] = a1; s2[p] = a2; dq[p] = aq; dk[p] = ak;
    }
    float c0 = lds[O_C + 0], cq = lds[O_C + 1], ck = lds[O_C + 2];

    // ---- bilinear numerators: row-at-a-time over Gqk ----
    float num[NBK][NBK] = {{0.f,0.f,0.f},{0.f,0.f,0.f},{0.f,0.f,0.f}};
    #pragma unroll 5
    for (int e = 0; e < BAD; ++e) {
        float t0 = 0.f, t1 = 0.f, t2 = 0.f;
        #pragma unroll
        for (int f = 0; f < BAD; ++f) {
            float g = lds[O_GQK + e * STR + f];
            t0 += g * ba[0 * BAD + f];
            t1 += g * ba[1 * BAD + f];
            t2 += g * ba[2 * BAD + f];
        }
        #pragma unroll
        for (int i = 0; i < NBK; ++i) {
            float be = ba[i * BAD + e];
            num[i][0] += be * t0;
            num[i][1] += be * t1;
            num[i][2] += be * t2;
        }
    }

    // ---- quadratic forms via scaled lower triangles ----
    float qn2[NBK] = {0.f, 0.f, 0.f}, kn2[NBK] = {0.f, 0.f, 0.f};
    #pragma unroll 5
    for (int e = 0; e < BAD; ++e) {
        float pq0 = 0.f, pq1 = 0.f, pq2 = 0.f;
        float pk0 = 0.f, pk1 = 0.f, pk2 = 0.f;
        for (int f = 0; f <= e; ++f) {
            float gq = lds[O_GQQ + e * STR + f];
            float gk = lds[O_GKK + e * STR + f];
            float b0 = ba[0 * BAD + f], b1v = ba[1 * BAD + f], b2v = ba[2 * BAD + f];
            pq0 += gq * b0; pq1 += gq * b1v; pq2 += gq * b2v;
            pk0 += gk * b0; pk1 += gk * b1v; pk2 += gk * b2v;
        }
        qn2[0] += ba[0 * BAD + e] * pq0;
        qn2[1] += ba[1 * BAD + e] * pq1;
        qn2[2] += ba[2 * BAD + e] * pq2;
        kn2[0] += ba[0 * BAD + e] * pk0;
        kn2[1] += ba[1 * BAD + e] * pk1;
        kn2[2] += ba[2 * BAD + e] * pk2;
    }
    #pragma unroll
    for (int p = 0; p < NBK; ++p) {
        qn2[p] += 2.0f * dq[p] + cq;
        kn2[p] += 2.0f * dk[p] + ck;
    }

    // ---- softmax over j ----
    float att[NBK][NBK];
    {
        float kn[NBK];
        #pragma unroll
        for (int j = 0; j < NBK; ++j) kn[j] = __builtin_amdgcn_sqrtf(fmaxf(kn2[j], 0.0f));
        #pragma unroll
        for (int i = 0; i < NBK; ++i) {
            float qn = __builtin_amdgcn_sqrtf(fmaxf(qn2[i], 0.0f));
            float dv[NBK];
            #pragma unroll
            for (int j = 0; j < NBK; ++j)
                dv[j] = (num[i][j] + s1[i] + s2[j] + c0) *
                        __builtin_amdgcn_rcpf(fmaxf(qn * kn[j], EPS));
            float mx = fmaxf(dv[0], fmaxf(dv[1], dv[2]));
            float e0 = __expf(dv[0] - mx);
            float e1 = __expf(dv[1] - mx);
            float e2 = __expf(dv[2] - mx);
            float inv = __builtin_amdgcn_rcpf(e0 + e1 + e2);
            att[i][0] = e0 * inv;
            att[i][1] = e1 * inv;
            att[i][2] = e2 * inv;
        }
    }

    // ---- r2 init from base (states) + b2, before ba overwrite ----
    float r2[NBK * SS];
    #pragma unroll
    for (int i = 0; i < NBK; ++i)
        #pragma unroll
        for (int o = 0; o < SS; ++o) r2[i * SS + o] = ba[i * BAD + o] + lds[O_B2 + o];

    // ---- a_tilde_i = sum_j att[i][j] * ba_j (in place) ----
    #pragma unroll
    for (int e = 0; e < BAD; ++e) {
        float b0 = ba[0 * BAD + e], b1v = ba[1 * BAD + e], b2v = ba[2 * BAD + e];
        ba[0 * BAD + e] = att[0][0] * b0 + att[0][1] * b1v + att[0][2] * b2v;
        ba[1 * BAD + e] = att[1][0] * b0 + att[1][1] * b1v + att[1][2] * b2v;
        ba[2 * BAD + e] = att[2][0] * b0 + att[2][1] * b1v + att[2][2] * b2v;
    }

    // ---- main VD loop ----
    #pragma unroll 2
    for (int d = 0; d < VD; ++d) {
        float m0 = lds[O_MB + d];
        float acc0 = m0, acc1 = m0, acc2 = m0;
        #pragma unroll
        for (int e = 0; e < BAD; ++e) {
            float m = lds[O_M + d * STR + e];
            acc0 += m * ba[0 * BAD + e];
            acc1 += m * ba[1 * BAD + e];
            acc2 += m * ba[2 * BAD + e];
        }
        // tanh(x) = 1 - 2/(1+exp(2x)); acc already = 2x (M,mb doubled in prep)
        float r10 = fmaf(-2.0f, __builtin_amdgcn_rcpf(1.0f + __expf(acc0)), 1.0f);
        float r11 = fmaf(-2.0f, __builtin_amdgcn_rcpf(1.0f + __expf(acc1)), 1.0f);
        float r12 = fmaf(-2.0f, __builtin_amdgcn_rcpf(1.0f + __expf(acc2)), 1.0f);
        #pragma unroll
        for (int o = 0; o < SS; ++o) {
            float w = lds[O_W2T + d * 16 + o];
            r2[0 * SS + o] += r10 * w;
            r2[1 * SS + o] += r11 * w;
            r2[2 * SS + o] += r12 * w;
        }
    }

    // ---- store ----
    float* op = out + (long)elem * OUTD;
    #pragma unroll
    for (int k = 0; k < NBK * SS; ++k) op[k] = r2[k];
    op[48] = conf0;
    op[49] = conf1;
    op[50] = conf2;
}

extern "C" void kernel_launch(void* const* d_in, const int* in_sizes, int n_in,
                              void* d_out, int out_size, void* d_ws, size_t ws_size,
                              hipStream_t stream) {
    const float* states = (const float*)d_in[0];
    const float* action = (const float*)d_in[1];
    const int* block_id = (const int*)d_in[2];
    const float* Wq = (const float*)d_in[3];
    const float* bq = (const float*)d_in[4];
    const float* Wk = (const float*)d_in[5];
    const float* bk = (const float*)d_in[6];
    const float* Wv = (const float*)d_in[7];
    const float* bv = (const float*)d_in[8];
    const float* W1 = (const float*)d_in[9];
    const float* b1 = (const float*)d_in[10];
    const float* W2 = (const float*)d_in[11];
    const float* b2 = (const float*)d_in[12];
    const float* Wc1 = (const float*)d_in[13];
    const float* bc1 = (const float*)d_in[14];
    const float* Wc2 = (const float*)d_in[15];
    const float* bc2 = (const float*)d_in[16];
    float* out = (float*)d_out;
    float* ws = (float*)d_ws;

    hipLaunchKernelGGL(prep_kernel, dim3((LDS_F + 255) / 256), dim3(256), 0, stream,
                       Wq, bq, Wk, bk, Wv, bv, W1, b1, W2, b2, Wc1, bc1, Wc2, bc2, ws);
    hipLaunchKernelGGL(main_kernel, dim3(BTOT / 256), dim3(256), 0, stream,
                       states, action, block_id, ws, out);
}